// Round 5
// baseline (2899.168 us; speedup 1.0000x reference)
//
#include <hip/hip_runtime.h>
#include <math.h>

#define BN 64
#define KIN 1024
#define DOUT 512
#define NN 2048
#define TBLK 128
#define NBLK 16

__device__ __forceinline__ float softplus_f(float x) {
  float e = __expf(-fabsf(x));
  return fmaxf(x, 0.f) + __logf(1.f + e);
}
__device__ __forceinline__ float apply_nl(int id, float v) {
  switch (id) {
    case 0: return fmaxf(v, 0.f);
    case 1: { float e = __expf(2.f * v); return fmaf(-2.f, __builtin_amdgcn_rcpf(e + 1.f), 1.f); }
    case 2: return v >= 0.f ? v : 0.01f * v;
    case 3: return v;
    case 4: return __sinf(v);
    case 5: return softplus_f(v);
    default: return v - softplus_f(v);  // -softplus(-v)
  }
}

// ---------------- adj dtype detection (parallel) ----------------
__global__ void detect_adj(const unsigned int* __restrict__ a, int* __restrict__ flags) {
  int idx = blockIdx.x * 256 + threadIdx.x;  // 16384 dwords = first 64 KiB
  unsigned int v = a[idx];
  bool bad = ((v & 0xFFu) > 1u) || (((v >> 8) & 0xFFu) > 1u) ||
             (((v >> 16) & 0xFFu) > 1u) || ((v >> 24) > 1u);
  bool off = (v & 0xFFFFFF00u) != 0u;
  if (__any(bad) && (threadIdx.x & 63) == 0) atomicOr(&flags[0], 1);
  if (__any(off) && (threadIdx.x & 63) == 0) atomicOr(&flags[1], 1);
}

__global__ void normalize_adj(const unsigned char* __restrict__ a,
                              const int* __restrict__ flags,
                              unsigned char* __restrict__ out) {
  size_t i = (size_t)blockIdx.x * blockDim.x + threadIdx.x;
  int mode = flags[0] ? 2 : (flags[1] ? 1 : 0);
  unsigned char r;
  if (mode == 1)      r = (a[i] != 0);
  else if (mode == 0) r = (((const int*)a)[i] != 0);
  else                r = (((const float*)a)[i] != 0.f);
  out[i] = r;
}

// ---------------- X transpose ----------------
__global__ void transpose_x(const float* __restrict__ X, float* __restrict__ XT) {
  int g = blockIdx.x * blockDim.x + threadIdx.x;
  int k = g >> 6, b = g & 63;
  XT[g] = X[(size_t)b * KIN + k];
}

// ---------------- pack in-block triangles ----------------
__global__ __launch_bounds__(256) void pack_wmid(const float* __restrict__ Wmid,
                                                 const unsigned char* __restrict__ adjN,
                                                 float* __restrict__ wpack) {
  int g = blockIdx.x * 256 + threadIdx.x;  // 65536 float4s
  int i = g >> 12;
  int rem = g & 4095;
  int j = rem >> 5;
  int q4 = (rem & 31) * 4;
  int n0 = 1 + i * TBLK;
  int size = NN - 1 - n0;
  if (size > TBLK) size = TBLK;
  float w[4];
#pragma unroll
  for (int e = 0; e < 4; ++e) {
    int q = q4 + e;
    float v = 0.f;
    if (q > j && j < size && q < size) {
      size_t idx = (size_t)(n0 + j) * NN + (size_t)(n0 + q);
      v = Wmid[idx] * (float)adjN[idx];
    }
    w[e] = v;
  }
  *(float4*)(wpack + (size_t)g * 4) = make_float4(w[0], w[1], w[2], w[3]);
}

// ---------------- unified partial GEMM ----------------
// MODE 0: no mask, atomic acc. MODE 1: element mask, atomic acc.
// MODE 2: row mask (adj[:,NN-1]), atomic acc.
// MODE 3: element mask, single K-chunk, NON-atomic += (one owner per output).
template <int MODE>
__global__ __launch_bounds__(256) void gemm_partial(
    const float* __restrict__ AT, const float* __restrict__ W,
    const unsigned char* __restrict__ adj, float* __restrict__ accT,
    int ldw, int col0, int ncols, int kPerChunk, int nColTiles)
{
  const int ct = blockIdx.x % nColTiles;
  const int kc = blockIdx.x / nColTiles;
  const int c0 = ct * 64;
  const int k0 = kc * kPerChunk;
  const int t = threadIdx.x;
  const int tb = t >> 4;
  const int tc = t & 15;

  __shared__ __align__(16) float At[16][64];
  __shared__ __align__(16) float Wt[16][64];

  float acc[4][4] = {};
  const int sk = t >> 4;
  const int sq = t & 15;

  for (int ks = k0; ks < k0 + kPerChunk; ks += 16) {
    const float4 av = *(const float4*)(AT + (size_t)(ks + sk) * 64 + sq * 4);
    *(float4*)(&At[sk][sq * 4]) = av;
    {
      const float* wrow = W + (size_t)(ks + sk) * ldw + col0;
      float w[4];
      float rowmask = 1.f;
      if (MODE == 2) rowmask = (float)adj[(size_t)(ks + sk) * NN + (NN - 1)];
#pragma unroll
      for (int e = 0; e < 4; ++e) {
        int cl = c0 + sq * 4 + e;
        float wv = 0.f;
        if (cl < ncols) {
          wv = wrow[cl];
          if (MODE == 1 || MODE == 3) wv *= (float)adj[(size_t)(ks + sk) * NN + col0 + cl];
          if (MODE == 2) wv *= rowmask;
        }
        w[e] = wv;
      }
      *(float4*)(&Wt[sk][sq * 4]) = make_float4(w[0], w[1], w[2], w[3]);
    }
    __syncthreads();
#pragma unroll
    for (int kk = 0; kk < 16; ++kk) {
      float a4[4], w4[4];
#pragma unroll
      for (int e = 0; e < 4; ++e) a4[e] = At[kk][tb * 4 + e];
#pragma unroll
      for (int e = 0; e < 4; ++e) w4[e] = Wt[kk][tc * 4 + e];
#pragma unroll
      for (int i = 0; i < 4; ++i)
#pragma unroll
        for (int j = 0; j < 4; ++j) acc[i][j] = fmaf(a4[i], w4[j], acc[i][j]);
    }
    __syncthreads();
  }

#pragma unroll
  for (int j = 0; j < 4; ++j) {
    int cl = c0 + tc * 4 + j;
    if (cl < ncols) {
      float* dst = accT + (size_t)(col0 + cl) * 64 + tb * 4;
      if (MODE == 3) {
#pragma unroll
        for (int i = 0; i < 4; ++i) dst[i] += acc[i][j];
      } else {
#pragma unroll
        for (int i = 0; i < 4; ++i) atomicAdd(dst + i, acc[i][j]);
      }
    }
  }
}

// ---------------- init finish ----------------
__global__ void init_finish(const float* __restrict__ out0accT, const float* __restrict__ b0,
                            const unsigned char* __restrict__ adjN, const int* __restrict__ nl_idx,
                            float* __restrict__ curT) {
  int g = blockIdx.x * blockDim.x + threadIdx.x;
  int n = g >> 6;
  float v = out0accT[g] + b0[n];
  v = apply_nl(nl_idx[0], v);
  curT[g] = adjN[n] ? v : 0.f;
}

// ---------------- sequential in-block solver (R3-proven) + deltaG export ----------------
__global__ __launch_bounds__(256, 1) void seq_block(
    const float* __restrict__ wpack, const int* __restrict__ nlidx,
    const float* __restrict__ bmid, const float* __restrict__ CaccT,
    float* __restrict__ curT, float* __restrict__ deltaG,
    int blk, int n0, int size)
{
  __shared__ __align__(16) float wmS[TBLK][TBLK];   // 64 KiB packed triangle
  __shared__ __align__(16) float deltaS[32][64];    // 8 KiB broadcast
  const int tid = threadIdx.x;
  const int wv = tid >> 6;
  const int b = tid & 63;
  const int qbase = wv * 32;

  // ---- stage weights: clean float4 copy of pre-packed triangle (reg-staged) ----
  const float4* src = (const float4*)(wpack + (size_t)blk * TBLK * TBLK);
  float4 stg[16];
#pragma unroll
  for (int it = 0; it < 16; ++it) stg[it] = src[it * 256 + tid];

  // ---- preload this wave's slot state (overlaps staging latency) ----
  float val[32], iv[32];
  int id[32];
#pragma unroll
  for (int l = 0; l < 32; ++l) {
    int q = qbase + l;
    int n = n0 + q;
    bool ok = q < size;
    val[l] = ok ? (CaccT[(size_t)n * 64 + b] + bmid[n]) : 0.f;
    iv[l] = ok ? curT[(size_t)n * 64 + b] : 0.f;
    id[l] = ok ? nlidx[n] : 3;
  }

#pragma unroll
  for (int it = 0; it < 16; ++it)
    *(float4*)(&((float*)wmS)[(size_t)(it * 256 + tid) * 4]) = stg[it];
  __syncthreads();

#pragma unroll 1
  for (int c = 0; c < 4; ++c) {
    if (wv == c) {
      // -------- Phase A: serial over own 32 slots, row prefetched --------
      const int jbase = c * 32;
      float4 wrow[8];
      {
        const float4* wr = (const float4*)(&wmS[jbase][qbase]);
#pragma unroll
        for (int g2 = 0; g2 < 8; ++g2) wrow[g2] = wr[g2];
      }
#pragma unroll
      for (int jj = 0; jj < 32; ++jj) {
        const int j = jbase + jj;
        float delta = 0.f;
        if (j < size) {  // wave-uniform
          float nv = apply_nl(__builtin_amdgcn_readfirstlane(id[jj]), val[jj]);
          delta = nv - iv[jj];
          curT[(size_t)(n0 + j) * 64 + b] = nv;  // fire-and-forget
        }
        deltaS[jj][b] = delta;
        deltaG[(size_t)blk * TBLK * 64 + (size_t)j * 64 + b] = delta;
        float4 wnext[8];
        if (jj < 31) {
          const float4* wr2 = (const float4*)(&wmS[j + 1][qbase]);
#pragma unroll
          for (int g2 = 0; g2 < 8; ++g2) wnext[g2] = wr2[g2];
        }
#pragma unroll
        for (int g2 = (jj + 1) >> 2; g2 < 8; ++g2) {
          val[g2 * 4 + 0] = fmaf(delta, wrow[g2].x, val[g2 * 4 + 0]);
          val[g2 * 4 + 1] = fmaf(delta, wrow[g2].y, val[g2 * 4 + 1]);
          val[g2 * 4 + 2] = fmaf(delta, wrow[g2].z, val[g2 * 4 + 2]);
          val[g2 * 4 + 3] = fmaf(delta, wrow[g2].w, val[g2 * 4 + 3]);
        }
        if (jj < 31) {
#pragma unroll
          for (int g2 = 0; g2 < 8; ++g2) wrow[g2] = wnext[g2];
        }
      }
    }
    __syncthreads();  // deltas visible
    if (wv > c) {
      // -------- Phase B: rank-32 update of own slots --------
#pragma unroll
      for (int jj = 0; jj < 32; ++jj) {
        const int j = c * 32 + jj;
        const float delta = deltaS[jj][b];
        const float4* wr = (const float4*)(&wmS[j][qbase]);
#pragma unroll
        for (int l8 = 0; l8 < 8; ++l8) {
          float4 w4 = wr[l8];
          val[l8 * 4 + 0] = fmaf(delta, w4.x, val[l8 * 4 + 0]);
          val[l8 * 4 + 1] = fmaf(delta, w4.y, val[l8 * 4 + 1]);
          val[l8 * 4 + 2] = fmaf(delta, w4.z, val[l8 * 4 + 2]);
          val[l8 * 4 + 3] = fmaf(delta, w4.w, val[l8 * 4 + 3]);
        }
      }
    }
    __syncthreads();  // deltaS reusable
  }
}

// ---------------- final finish ----------------
__global__ void final_finish(const float* __restrict__ outaccT, const float* __restrict__ bout,
                             const int* __restrict__ nlidx, float* __restrict__ out) {
  int g = blockIdx.x * blockDim.x + threadIdx.x;
  int c = g >> 6, b = g & 63;
  float v = outaccT[g] + bout[c];
  v = apply_nl(nlidx[NN - 1], v);
  out[(size_t)b * DOUT + c] = v;
}

// ---------------- state transpose ----------------
__global__ __launch_bounds__(256) void transpose_state(const float* __restrict__ curT,
                                                       float* __restrict__ stateOut) {
  __shared__ float tile[64][65];
  int n0 = blockIdx.x * 64;
  for (int r = 0; r < 16; ++r) {
    int e = r * 256 + threadIdx.x;
    tile[e >> 6][e & 63] = curT[(size_t)(n0 + (e >> 6)) * 64 + (e & 63)];
  }
  __syncthreads();
  for (int r = 0; r < 16; ++r) {
    int e = r * 256 + threadIdx.x;
    int bb = e >> 6, nn2 = e & 63;
    stateOut[(size_t)bb * NN + n0 + nn2] = tile[nn2][bb];
  }
}

extern "C" void kernel_launch(void* const* d_in, const int* in_sizes, int n_in,
                              void* d_out, int out_size, void* d_ws, size_t ws_size,
                              hipStream_t stream) {
  const float* X = (const float*)d_in[0];
  const unsigned char* adj = (const unsigned char*)d_in[1];
  const int* nl_idx = (const int*)d_in[2];
  const float* W0 = (const float*)d_in[3];
  const float* b0 = (const float*)d_in[4];
  const float* W_mid = (const float*)d_in[5];
  const float* b_mid = (const float*)d_in[6];
  const float* W_out = (const float*)d_in[7];
  const float* b_out = (const float*)d_in[8];
  float* out = (float*)d_out;
  float* stateOut = out + BN * DOUT;

  char* ws = (char*)d_ws;
  unsigned char* adjN = (unsigned char*)(ws + 0);       // 4 MiB
  int* flags = (int*)(ws + 4194304);                    // 256 B
  float* XT = (float*)(ws + 4194560);                   // 256 KiB
  float* curT = (float*)(ws + 4456704);                 // 512 KiB
  float* CbaseT = (float*)(ws + 4980992);               // 512 KiB (zeroed acc, updated in place)
  float* out0accT = (float*)(ws + 5505280);             // 512 KiB (zeroed acc)
  float* outaccT = (float*)(ws + 6029568);              // 128 KiB (zeroed acc)
  float* wpack = (float*)(ws + 6160640);                // 1 MiB
  float* deltaG = (float*)(ws + 7209216);               // 512 KiB -> end 7733504

  hipMemsetAsync(flags, 0, 256, stream);
  hipMemsetAsync(CbaseT, 0, 524288 + 524288 + 131072, stream);

  detect_adj<<<64, 256, 0, stream>>>((const unsigned int*)adj, flags);
  normalize_adj<<<16384, 256, 0, stream>>>(adj, flags, adjN);
  transpose_x<<<256, 256, 0, stream>>>(X, XT);
  pack_wmid<<<256, 256, 0, stream>>>(W_mid, adjN, wpack);

  // node 0: out0accT = X @ W0
  gemm_partial<0><<<128, 256, 0, stream>>>(XT, W0, adjN, out0accT, NN, 0, NN, 256, 32);
  init_finish<<<512, 256, 0, stream>>>(out0accT, b0, adjN, nl_idx, curT);

  // Cbase: state_0 @ (W_mid * adj) for ALL columns (one big parallel GEMM)
  gemm_partial<1><<<256, 256, 0, stream>>>(curT, W_mid, adjN, CbaseT, NN, 0, NN, 256, 32);

  // sequential middle: solve block j, then rank-128 update of all later columns
  for (int j = 0; j < NBLK; ++j) {
    int n0 = 1 + j * TBLK;
    int size = NN - 1 - n0;
    if (size > TBLK) size = TBLK;
    seq_block<<<1, 256, 0, stream>>>(wpack, nl_idx, b_mid, CbaseT, curT, deltaG, j, n0, size);
    if (j < NBLK - 1) {
      int rowbase = n0;                 // 128 rows of block j
      int col0 = 1 + (j + 1) * TBLK;    // first column of block j+1
      int ncols = (NN - 1) - col0;      // middle cols only (n <= 2046)
      int tiles = (ncols + 63) / 64;
      gemm_partial<3><<<tiles, 256, 0, stream>>>(
          deltaG + (size_t)j * TBLK * 64, W_mid + (size_t)rowbase * NN,
          adjN + (size_t)rowbase * NN, CbaseT, NN, col0, ncols, TBLK, tiles);
    }
  }

  gemm_partial<2><<<64, 256, 0, stream>>>(curT, W_out, adjN, outaccT, DOUT, 0, DOUT, 256, 8);
  final_finish<<<128, 256, 0, stream>>>(outaccT, b_out, nl_idx, out);
  transpose_state<<<32, 256, 0, stream>>>(curT, stateOut);
}

// Round 6
// 1044.353 us; speedup vs baseline: 2.7760x; 2.7760x over previous
//
#include <hip/hip_runtime.h>
#include <math.h>

#define BN 64
#define KIN 1024
#define DOUT 512
#define NN 2048
#define TBLK 128
#define NBLK 16

__device__ __forceinline__ float softplus_f(float x) {
  float e = __expf(-fabsf(x));
  return fmaxf(x, 0.f) + __logf(1.f + e);
}
__device__ __forceinline__ float apply_nl(int id, float v) {
  switch (id) {
    case 0: return fmaxf(v, 0.f);
    case 1: { float e = __expf(2.f * v); return fmaf(-2.f, __builtin_amdgcn_rcpf(e + 1.f), 1.f); }
    case 2: return v >= 0.f ? v : 0.01f * v;
    case 3: return v;
    case 4: return __sinf(v);
    case 5: return softplus_f(v);
    default: return v - softplus_f(v);  // -softplus(-v)
  }
}

// ---------------- adj dtype detection (parallel) ----------------
__global__ void detect_adj(const unsigned int* __restrict__ a, int* __restrict__ flags) {
  int idx = blockIdx.x * 256 + threadIdx.x;  // 16384 dwords = first 64 KiB
  unsigned int v = a[idx];
  bool bad = ((v & 0xFFu) > 1u) || (((v >> 8) & 0xFFu) > 1u) ||
             (((v >> 16) & 0xFFu) > 1u) || ((v >> 24) > 1u);
  bool off = (v & 0xFFFFFF00u) != 0u;
  if (__any(bad) && (threadIdx.x & 63) == 0) atomicOr(&flags[0], 1);
  if (__any(off) && (threadIdx.x & 63) == 0) atomicOr(&flags[1], 1);
}

__global__ void normalize_adj(const unsigned char* __restrict__ a,
                              const int* __restrict__ flags,
                              unsigned char* __restrict__ out) {
  size_t i = (size_t)blockIdx.x * blockDim.x + threadIdx.x;
  int mode = flags[0] ? 2 : (flags[1] ? 1 : 0);
  unsigned char r;
  if (mode == 1)      r = (a[i] != 0);
  else if (mode == 0) r = (((const int*)a)[i] != 0);
  else                r = (((const float*)a)[i] != 0.f);
  out[i] = r;
}

// ---------------- X transpose ----------------
__global__ void transpose_x(const float* __restrict__ X, float* __restrict__ XT) {
  int g = blockIdx.x * blockDim.x + threadIdx.x;
  int k = g >> 6, b = g & 63;
  XT[g] = X[(size_t)b * KIN + k];
}

// ---------------- pack in-block triangles ----------------
__global__ __launch_bounds__(256) void pack_wmid(const float* __restrict__ Wmid,
                                                 const unsigned char* __restrict__ adjN,
                                                 float* __restrict__ wpack) {
  int g = blockIdx.x * 256 + threadIdx.x;  // 65536 float4s
  int i = g >> 12;
  int rem = g & 4095;
  int j = rem >> 5;
  int q4 = (rem & 31) * 4;
  int n0 = 1 + i * TBLK;
  int size = NN - 1 - n0;
  if (size > TBLK) size = TBLK;
  float w[4];
#pragma unroll
  for (int e = 0; e < 4; ++e) {
    int q = q4 + e;
    float v = 0.f;
    if (q > j && j < size && q < size) {
      size_t idx = (size_t)(n0 + j) * NN + (size_t)(n0 + q);
      v = Wmid[idx] * (float)adjN[idx];
    }
    w[e] = v;
  }
  *(float4*)(wpack + (size_t)g * 4) = make_float4(w[0], w[1], w[2], w[3]);
}

// ---------------- unified partial GEMM ----------------
// MODE 0: no mask, atomic acc. MODE 1: element mask, atomic acc.
// MODE 2: row mask (adj[:,NN-1]), atomic acc.
template <int MODE>
__global__ __launch_bounds__(256) void gemm_partial(
    const float* __restrict__ AT, const float* __restrict__ W,
    const unsigned char* __restrict__ adj, float* __restrict__ accT,
    int ldw, int col0, int ncols, int kPerChunk, int nColTiles)
{
  const int ct = blockIdx.x % nColTiles;
  const int kc = blockIdx.x / nColTiles;
  const int c0 = ct * 64;
  const int k0 = kc * kPerChunk;
  const int t = threadIdx.x;
  const int tb = t >> 4;
  const int tc = t & 15;

  __shared__ __align__(16) float At[16][64];
  __shared__ __align__(16) float Wt[16][64];

  float acc[4][4] = {};
  const int sk = t >> 4;
  const int sq = t & 15;

  for (int ks = k0; ks < k0 + kPerChunk; ks += 16) {
    const float4 av = *(const float4*)(AT + (size_t)(ks + sk) * 64 + sq * 4);
    *(float4*)(&At[sk][sq * 4]) = av;
    {
      const float* wrow = W + (size_t)(ks + sk) * ldw + col0;
      float w[4];
      float rowmask = 1.f;
      if (MODE == 2) rowmask = (float)adj[(size_t)(ks + sk) * NN + (NN - 1)];
#pragma unroll
      for (int e = 0; e < 4; ++e) {
        int cl = c0 + sq * 4 + e;
        float wv = 0.f;
        if (cl < ncols) {
          wv = wrow[cl];
          if (MODE == 1) wv *= (float)adj[(size_t)(ks + sk) * NN + col0 + cl];
          if (MODE == 2) wv *= rowmask;
        }
        w[e] = wv;
      }
      *(float4*)(&Wt[sk][sq * 4]) = make_float4(w[0], w[1], w[2], w[3]);
    }
    __syncthreads();
#pragma unroll
    for (int kk = 0; kk < 16; ++kk) {
      float a4[4], w4[4];
#pragma unroll
      for (int e = 0; e < 4; ++e) a4[e] = At[kk][tb * 4 + e];
#pragma unroll
      for (int e = 0; e < 4; ++e) w4[e] = Wt[kk][tc * 4 + e];
#pragma unroll
      for (int i = 0; i < 4; ++i)
#pragma unroll
        for (int j = 0; j < 4; ++j) acc[i][j] = fmaf(a4[i], w4[j], acc[i][j]);
    }
    __syncthreads();
  }

#pragma unroll
  for (int j = 0; j < 4; ++j) {
    int cl = c0 + tc * 4 + j;
    if (cl < ncols) {
      float* dst = accT + (size_t)(col0 + cl) * 64 + tb * 4;
#pragma unroll
      for (int i = 0; i < 4; ++i) atomicAdd(dst + i, acc[i][j]);
    }
  }
}

// ---------------- init finish ----------------
__global__ void init_finish(const float* __restrict__ out0accT, const float* __restrict__ b0,
                            const unsigned char* __restrict__ adjN, const int* __restrict__ nl_idx,
                            float* __restrict__ curT) {
  int g = blockIdx.x * blockDim.x + threadIdx.x;
  int n = g >> 6;
  float v = out0accT[g] + b0[n];
  v = apply_nl(nl_idx[0], v);
  curT[g] = adjN[n] ? v : 0.f;
}

// ---------------- sequential in-block solver (R3 structure; deltas via LDS) ----------------
__global__ __launch_bounds__(256, 1) void seq_block(
    const float* __restrict__ wpack, const int* __restrict__ nlidx,
    const float* __restrict__ bmid, const float* __restrict__ CaccT,
    float* __restrict__ curT, float* __restrict__ deltaG,
    int blk, int n0, int size)
{
  __shared__ __align__(16) float wmS[TBLK][TBLK];        // 64 KiB packed triangle
  __shared__ __align__(16) float deltaFull[TBLK][64];    // 32 KiB all deltas of this block
  const int tid = threadIdx.x;
  const int wv = tid >> 6;
  const int b = tid & 63;
  const int qbase = wv * 32;

  // ---- stage weights: clean float4 copy of pre-packed triangle (reg-staged) ----
  const float4* src = (const float4*)(wpack + (size_t)blk * TBLK * TBLK);
  float4 stg[16];
#pragma unroll
  for (int it = 0; it < 16; ++it) stg[it] = src[it * 256 + tid];

  // ---- preload this wave's slot state (overlaps staging latency) ----
  float val[32], iv[32];
  int id[32];
#pragma unroll
  for (int l = 0; l < 32; ++l) {
    int q = qbase + l;
    int n = n0 + q;
    bool ok = q < size;
    val[l] = ok ? (CaccT[(size_t)n * 64 + b] + bmid[n]) : 0.f;
    iv[l] = ok ? curT[(size_t)n * 64 + b] : 0.f;
    id[l] = ok ? nlidx[n] : 3;
  }

#pragma unroll
  for (int it = 0; it < 16; ++it)
    *(float4*)(&((float*)wmS)[(size_t)(it * 256 + tid) * 4]) = stg[it];
  __syncthreads();

#pragma unroll 1
  for (int c = 0; c < 4; ++c) {
    if (wv == c) {
      // -------- Phase A: serial over own 32 slots, row prefetched --------
      const int jbase = c * 32;
      float4 wrow[8];
      {
        const float4* wr = (const float4*)(&wmS[jbase][qbase]);
#pragma unroll
        for (int g2 = 0; g2 < 8; ++g2) wrow[g2] = wr[g2];
      }
#pragma unroll
      for (int jj = 0; jj < 32; ++jj) {
        const int j = jbase + jj;
        float delta = 0.f;
        if (j < size) {  // wave-uniform
          float nv = apply_nl(__builtin_amdgcn_readfirstlane(id[jj]), val[jj]);
          delta = nv - iv[jj];
          curT[(size_t)(n0 + j) * 64 + b] = nv;  // fire-and-forget
        }
        deltaFull[j][b] = delta;
        float4 wnext[8];
        if (jj < 31) {
          const float4* wr2 = (const float4*)(&wmS[j + 1][qbase]);
#pragma unroll
          for (int g2 = 0; g2 < 8; ++g2) wnext[g2] = wr2[g2];
        }
#pragma unroll
        for (int g2 = (jj + 1) >> 2; g2 < 8; ++g2) {
          val[g2 * 4 + 0] = fmaf(delta, wrow[g2].x, val[g2 * 4 + 0]);
          val[g2 * 4 + 1] = fmaf(delta, wrow[g2].y, val[g2 * 4 + 1]);
          val[g2 * 4 + 2] = fmaf(delta, wrow[g2].z, val[g2 * 4 + 2]);
          val[g2 * 4 + 3] = fmaf(delta, wrow[g2].w, val[g2 * 4 + 3]);
        }
        if (jj < 31) {
#pragma unroll
          for (int g2 = 0; g2 < 8; ++g2) wrow[g2] = wnext[g2];
        }
      }
    }
    __syncthreads();  // deltas visible
    if (wv > c) {
      // -------- Phase B: rank-32 update of own slots --------
#pragma unroll
      for (int jj = 0; jj < 32; ++jj) {
        const int j = c * 32 + jj;
        const float delta = deltaFull[j][b];
        const float4* wr = (const float4*)(&wmS[j][qbase]);
#pragma unroll
        for (int l8 = 0; l8 < 8; ++l8) {
          float4 w4 = wr[l8];
          val[l8 * 4 + 0] = fmaf(delta, w4.x, val[l8 * 4 + 0]);
          val[l8 * 4 + 1] = fmaf(delta, w4.y, val[l8 * 4 + 1]);
          val[l8 * 4 + 2] = fmaf(delta, w4.z, val[l8 * 4 + 2]);
          val[l8 * 4 + 3] = fmaf(delta, w4.w, val[l8 * 4 + 3]);
        }
      }
    }
    __syncthreads();
  }

  // ---- export all deltas: coalesced float4 copy (off the serial path) ----
  {
    float4* dst = (float4*)(deltaG + (size_t)blk * TBLK * 64);
    const float4* sdel = (const float4*)&deltaFull[0][0];
#pragma unroll
    for (int it = 0; it < 8; ++it) dst[it * 256 + tid] = sdel[it * 256 + tid];
  }
}

// ---------------- final finish ----------------
__global__ void final_finish(const float* __restrict__ outaccT, const float* __restrict__ bout,
                             const int* __restrict__ nlidx, float* __restrict__ out) {
  int g = blockIdx.x * blockDim.x + threadIdx.x;
  int c = g >> 6, b = g & 63;
  float v = outaccT[g] + bout[c];
  v = apply_nl(nlidx[NN - 1], v);
  out[(size_t)b * DOUT + c] = v;
}

// ---------------- state transpose ----------------
__global__ __launch_bounds__(256) void transpose_state(const float* __restrict__ curT,
                                                       float* __restrict__ stateOut) {
  __shared__ float tile[64][65];
  int n0 = blockIdx.x * 64;
  for (int r = 0; r < 16; ++r) {
    int e = r * 256 + threadIdx.x;
    tile[e >> 6][e & 63] = curT[(size_t)(n0 + (e >> 6)) * 64 + (e & 63)];
  }
  __syncthreads();
  for (int r = 0; r < 16; ++r) {
    int e = r * 256 + threadIdx.x;
    int bb = e >> 6, nn2 = e & 63;
    stateOut[(size_t)bb * NN + n0 + nn2] = tile[nn2][bb];
  }
}

extern "C" void kernel_launch(void* const* d_in, const int* in_sizes, int n_in,
                              void* d_out, int out_size, void* d_ws, size_t ws_size,
                              hipStream_t stream) {
  const float* X = (const float*)d_in[0];
  const unsigned char* adj = (const unsigned char*)d_in[1];
  const int* nl_idx = (const int*)d_in[2];
  const float* W0 = (const float*)d_in[3];
  const float* b0 = (const float*)d_in[4];
  const float* W_mid = (const float*)d_in[5];
  const float* b_mid = (const float*)d_in[6];
  const float* W_out = (const float*)d_in[7];
  const float* b_out = (const float*)d_in[8];
  float* out = (float*)d_out;
  float* stateOut = out + BN * DOUT;

  char* ws = (char*)d_ws;
  unsigned char* adjN = (unsigned char*)(ws + 0);       // 4 MiB
  int* flags = (int*)(ws + 4194304);                    // 256 B
  float* XT = (float*)(ws + 4194560);                   // 256 KiB
  float* curT = (float*)(ws + 4456704);                 // 512 KiB
  float* CbaseT = (float*)(ws + 4980992);               // 512 KiB (zeroed acc, updated in place)
  float* out0accT = (float*)(ws + 5505280);             // 512 KiB (zeroed acc)
  float* outaccT = (float*)(ws + 6029568);              // 128 KiB (zeroed acc)
  float* wpack = (float*)(ws + 6160640);                // 1 MiB
  float* deltaG = (float*)(ws + 7209216);               // 512 KiB -> end 7733504

  hipMemsetAsync(flags, 0, 256, stream);
  hipMemsetAsync(CbaseT, 0, 524288 + 524288 + 131072, stream);

  detect_adj<<<64, 256, 0, stream>>>((const unsigned int*)adj, flags);
  normalize_adj<<<16384, 256, 0, stream>>>(adj, flags, adjN);
  transpose_x<<<256, 256, 0, stream>>>(X, XT);
  pack_wmid<<<256, 256, 0, stream>>>(W_mid, adjN, wpack);

  // node 0: out0accT = X @ W0
  gemm_partial<0><<<128, 256, 0, stream>>>(XT, W0, adjN, out0accT, NN, 0, NN, 256, 32);
  init_finish<<<512, 256, 0, stream>>>(out0accT, b0, adjN, nl_idx, curT);

  // Cbase: state_0 @ (W_mid * adj) for ALL columns (one big parallel GEMM)
  gemm_partial<1><<<256, 256, 0, stream>>>(curT, W_mid, adjN, CbaseT, NN, 0, NN, 256, 32);

  // sequential middle: solve block j, then rank-128 update of all later columns
  for (int j = 0; j < NBLK; ++j) {
    int n0 = 1 + j * TBLK;
    int size = NN - 1 - n0;
    if (size > TBLK) size = TBLK;
    seq_block<<<1, 256, 0, stream>>>(wpack, nl_idx, b_mid, CbaseT, curT, deltaG, j, n0, size);
    if (j < NBLK - 1) {
      int rowbase = n0;                 // 128 rows of block j
      int col0 = 1 + (j + 1) * TBLK;    // first column of block j+1
      int ncols = (NN - 1) - col0;      // middle cols only (n <= 2046)
      int tiles = (ncols + 63) / 64;
      // K=128 split into 2 chunks of 64, atomic accumulate into CbaseT
      gemm_partial<1><<<tiles * 2, 256, 0, stream>>>(
          deltaG + (size_t)j * TBLK * 64, W_mid + (size_t)rowbase * NN,
          adjN + (size_t)rowbase * NN, CbaseT, NN, col0, ncols, 64, tiles);
    }
  }

  gemm_partial<2><<<64, 256, 0, stream>>>(curT, W_out, adjN, outaccT, DOUT, 0, DOUT, 256, 8);
  final_finish<<<128, 256, 0, stream>>>(outaccT, b_out, nl_idx, out);
  transpose_state<<<32, 256, 0, stream>>>(curT, stateOut);
}